// Round 2
// baseline (1450.284 us; speedup 1.0000x reference)
//
#include <hip/hip_runtime.h>
#include <stdint.h>

#define NODES   8192
#define BATCH   8
#define FIN     16
#define HC1     64
#define HC2     1024
#define DTOT    1048576
#define NEG     0.2f

typedef unsigned short u16;

__device__ __forceinline__ float b2f(u16 s){ return __uint_as_float(((unsigned)s)<<16); }
__device__ __forceinline__ u16 f2b(float f){
    unsigned u = __float_as_uint(f);
    unsigned r = u + 0x7fffu + ((u>>16)&1u);
    return (u16)(r>>16);
}
__device__ __forceinline__ float lrelu(float x){ return x > 0.f ? x : NEG*x; }
// dtype-agnostic scalar load: isf ? fp32 : bf16
__device__ __forceinline__ float ldf(const void* p, long i, int isf){
    return isf ? ((const float*)p)[i] : b2f(((const u16*)p)[i]);
}

// ---------- detector: figure out float dtype (fp32 vs bf16) and edge dtype (i64 vs i32) ----------
__global__ void k_detect(const u16* __restrict__ xs, const int* __restrict__ ed, int* flags){
    __shared__ int cnt[2];
    int t = threadIdx.x;
    if(t<2) cnt[t]=0;
    __syncthreads();
    int bad=0;
    for(int i=t;i<1024;i+=256){
        u16 u = xs[i];               // safe: <= 2048 bytes into x under either dtype
        float a = fabsf(b2f(u));
        if(!(u==0 || (a>1e-8f && a<1e4f))) bad++;
    }
    if(bad) atomicAdd(&cnt[0], bad);
    int z=0;
    for(int i=t;i<1024;i+=256){
        if(ed[2*i+1]==0) z++;        // int64 high words are 0; int32 src values ~never 0
    }
    if(z) atomicAdd(&cnt[1], z);
    __syncthreads();
    if(t==0){ flags[0] = (cnt[0] > 64) ? 1 : 0; flags[1] = (cnt[1] > 512) ? 1 : 0; }
}

__device__ __forceinline__ int esrc(const int* e, int i, int i64){ return i64 ? e[2*i] : e[i]; }
__device__ __forceinline__ int edst(const int* e, int i, int E, int i64){ return i64 ? e[2*(E+i)] : e[E+i]; }

// ---------- zero scratch ----------
__global__ void k_zero(int* counts, float* v1a, float* adva){
    int i = blockIdx.x*256 + threadIdx.x;
    if(i < NODES) counts[i] = 0;
    if(i < 512)   v1a[i]  = 0.f;
    if(i < 128)   adva[i] = 0.f;
}

// ---------- degree count ----------
__global__ void k_count(const int* __restrict__ ed, int E, int* counts, const int* flags){
    int i64 = flags[1];
    int e = blockIdx.x*256 + threadIdx.x;
    if(e < E) atomicAdd(&counts[edst(ed,e,E,i64)], 1);
}

// ---------- exclusive scan (8192, one block) ----------
__global__ __launch_bounds__(1024) void k_scan(const int* __restrict__ counts, int* offs, int* cursor){
    __shared__ int sums[1024];
    int t = threadIdx.x;
    int base = t*8;
    int loc[8]; int s = 0;
    for(int k=0;k<8;k++){ loc[k] = s; s += counts[base+k]; }
    sums[t] = s;
    __syncthreads();
    for(int off=1; off<1024; off<<=1){
        int v = (t>=off) ? sums[t-off] : 0;
        __syncthreads();
        sums[t] += v;
        __syncthreads();
    }
    int b = (t==0) ? 0 : sums[t-1];
    for(int k=0;k<8;k++){ int v = b + loc[k]; offs[base+k]=v; cursor[base+k]=v; }
    if(t==1023) offs[NODES] = sums[1023];
}

// ---------- CSR fill ----------
__global__ void k_fill(const int* __restrict__ ed, int E, int* cursor, int* csr, const int* flags){
    int i64 = flags[1];
    int e = blockIdx.x*256 + threadIdx.x;
    if(e < E){ int p = atomicAdd(&cursor[edst(ed,e,E,i64)], 1); csr[p] = esrc(ed,e,i64); }
}

// ---------- dense1: g1 = x@W1 ; alphas ----------
__global__ __launch_bounds__(256) void k_dense1(const void* __restrict__ x,
        const void* __restrict__ W1, const void* __restrict__ asw, const void* __restrict__ adw,
        float* g1, float* as1, float* ad1, const int* flags){
    int isf = flags[0];
    __shared__ float w1[FIN*HC1];
    __shared__ float av[64], dv[64];
    __shared__ float xr[4][FIN];
    __shared__ float hrow[4][HC1];
    int t = threadIdx.x;
    int n0 = blockIdx.x*4;
    for(int i=t;i<FIN*HC1;i+=256) w1[i] = ldf(W1,i,isf);
    if(t<64){ av[t]=ldf(asw,t,isf); dv[t]=ldf(adw,t,isf); }
    if(t<64) xr[t>>4][t&15] = ldf(x, n0*FIN + t, isf);
    __syncthreads();
    int i = t>>6, c = t&63;
    float acc = 0.f;
    #pragma unroll
    for(int k=0;k<FIN;k++) acc += xr[i][k]*w1[k*HC1+c];
    g1[(n0+i)*HC1 + c] = acc;
    hrow[i][c] = acc;
    __syncthreads();
    if(t<32){
        int ii=t>>3, h=t&7;
        float sa=0.f, sd=0.f;
        #pragma unroll
        for(int k=0;k<8;k++){ float v=hrow[ii][h*8+k]; sa+=v*av[h*8+k]; sd+=v*dv[h*8+k]; }
        as1[(n0+ii)*8+h]=sa; ad1[(n0+ii)*8+h]=sd;
    }
}

// ---------- conv1 aggregation: 1 node / 64 threads ----------
__global__ __launch_bounds__(64) void k_agg1(const int* __restrict__ offs, const int* __restrict__ csr,
        const float* __restrict__ g1, const float* __restrict__ as1, const float* __restrict__ ad1,
        const void* __restrict__ b1, float* z1, const int* flags){
    int isf = flags[0];
    __shared__ float mh[8], dh[8], adl[8];
    int n = blockIdx.x, t = threadIdx.x;
    int off = offs[n], deg = offs[n+1]-off, tot = deg+1;
    if(t<8) adl[t] = ad1[n*8+t];
    __syncthreads();
    if(t<8){
        float ad = adl[t];
        float m = -1e30f;
        for(int j=0;j<tot;j++){
            int s = (j<deg)?csr[off+j]:n;
            float e = lrelu(as1[s*8+t] + ad);
            m = fmaxf(m, e);
        }
        float den = 1e-16f;
        for(int j=0;j<tot;j++){
            int s = (j<deg)?csr[off+j]:n;
            float e = lrelu(as1[s*8+t] + ad);
            den += __expf(e - m);
        }
        mh[t]=m; dh[t]=den;
    }
    __syncthreads();
    int c = t, h = t>>3;
    float m = mh[h], ad = adl[h];
    float acc = 0.f;
    for(int j=0;j<tot;j++){
        int s = (j<deg)?csr[off+j]:n;
        float e = lrelu(as1[s*8+h] + ad);
        float w = __expf(e - m);
        acc += w * g1[s*HC1 + c];
    }
    z1[n*HC1 + c] = fmaxf(acc/dh[h] + ldf(b1,c,isf), 0.f);
}

// ---------- dense2: g2 = z1@W2 (bf16 scratch out) ----------
__global__ __launch_bounds__(256) void k_dense2(const float* __restrict__ z1,
        const void* __restrict__ W2, u16* g2, const int* flags){
    int isf = flags[0];
    __shared__ float zr[8][HC1];
    int t = threadIdx.x;
    int n0 = blockIdx.x*8;
    for(int i=t;i<8*HC1;i+=256) zr[i>>6][i&63] = z1[n0*HC1 + i];
    __syncthreads();
    int c0 = t*4;
    float acc[8][4];
    #pragma unroll
    for(int i=0;i<8;i++){ acc[i][0]=0;acc[i][1]=0;acc[i][2]=0;acc[i][3]=0; }
    for(int k=0;k<HC1;k++){
        float w0,w1,w2,w3;
        if(isf){
            float4 w = *(const float4*)((const float*)W2 + (size_t)k*HC2 + c0);
            w0=w.x; w1=w.y; w2=w.z; w3=w.w;
        } else {
            ushort4 w = *(const ushort4*)((const u16*)W2 + (size_t)k*HC2 + c0);
            w0=b2f(w.x); w1=b2f(w.y); w2=b2f(w.z); w3=b2f(w.w);
        }
        #pragma unroll
        for(int i=0;i<8;i++){
            float zv = zr[i][k];
            acc[i][0]+=zv*w0; acc[i][1]+=zv*w1; acc[i][2]+=zv*w2; acc[i][3]+=zv*w3;
        }
    }
    #pragma unroll
    for(int i=0;i<8;i++){
        ushort4 o;
        o.x=f2b(acc[i][0]); o.y=f2b(acc[i][1]); o.z=f2b(acc[i][2]); o.w=f2b(acc[i][3]);
        *(ushort4*)&g2[(size_t)(n0+i)*HC2 + c0] = o;
    }
}

// ---------- alpha2 ----------
__global__ __launch_bounds__(256) void k_alpha2(const u16* __restrict__ g2,
        const void* __restrict__ asw, const void* __restrict__ adw,
        float* as2, float* ad2, const int* flags){
    int isf = flags[0];
    int n = blockIdx.x, t = threadIdx.x;
    int h = t>>5, l = t&31;
    int c = h*128 + l*4;
    ushort4 gv = *(const ushort4*)&g2[(size_t)n*HC2 + c];
    float s0,s1,s2,s3,d0,d1,d2,d3;
    if(isf){
        float4 sv = *(const float4*)((const float*)asw + c);
        float4 dv = *(const float4*)((const float*)adw + c);
        s0=sv.x;s1=sv.y;s2=sv.z;s3=sv.w; d0=dv.x;d1=dv.y;d2=dv.z;d3=dv.w;
    } else {
        ushort4 sv = *(const ushort4*)((const u16*)asw + c);
        ushort4 dv = *(const ushort4*)((const u16*)adw + c);
        s0=b2f(sv.x);s1=b2f(sv.y);s2=b2f(sv.z);s3=b2f(sv.w);
        d0=b2f(dv.x);d1=b2f(dv.y);d2=b2f(dv.z);d3=b2f(dv.w);
    }
    float g0=b2f(gv.x), g1v=b2f(gv.y), g2v=b2f(gv.z), g3=b2f(gv.w);
    float sa = g0*s0+g1v*s1+g2v*s2+g3*s3;
    float sd = g0*d0+g1v*d1+g2v*d2+g3*d3;
    for(int m=1;m<32;m<<=1){ sa += __shfl_xor(sa,m); sd += __shfl_xor(sd,m); }
    if(l==0){ as2[n*8+h]=sa; ad2[n*8+h]=sd; }
}

// ---------- conv2 aggregation: 1 node / 256 threads, writes h (bf16, [b][dtot] layout) ----------
__global__ __launch_bounds__(256) void k_agg2(const int* __restrict__ offs, const int* __restrict__ csr,
        const u16* __restrict__ g2, const float* __restrict__ as2, const float* __restrict__ ad2,
        const void* __restrict__ b2, u16* hbf, const int* flags){
    int isf = flags[0];
    __shared__ float mh[8], dh[8], adl[8];
    int n = blockIdx.x, t = threadIdx.x;
    int off = offs[n], deg = offs[n+1]-off, tot = deg+1;
    if(t<8) adl[t] = ad2[n*8+t];
    __syncthreads();
    if(t<8){
        float ad = adl[t];
        float m = -1e30f;
        for(int j=0;j<tot;j++){
            int s = (j<deg)?csr[off+j]:n;
            float e = lrelu(as2[s*8+t] + ad);
            m = fmaxf(m, e);
        }
        float den = 1e-16f;
        for(int j=0;j<tot;j++){
            int s = (j<deg)?csr[off+j]:n;
            float e = lrelu(as2[s*8+t] + ad);
            den += __expf(e - m);
        }
        mh[t]=m; dh[t]=den;
    }
    __syncthreads();
    int c0 = t*4, h = t>>5;
    float m = mh[h], ad = adl[h];
    float acc[4] = {0,0,0,0};
    for(int j=0;j<tot;j++){
        int s = (j<deg)?csr[off+j]:n;
        float e = lrelu(as2[s*8+h] + ad);
        float w = __expf(e - m);
        ushort4 gv = *(const ushort4*)&g2[(size_t)s*HC2 + c0];
        acc[0]+=w*b2f(gv.x); acc[1]+=w*b2f(gv.y); acc[2]+=w*b2f(gv.z); acc[3]+=w*b2f(gv.w);
    }
    float dhv = dh[h];
    ushort4 o;
    o.x = f2b(fmaxf(acc[0]/dhv + ldf(b2,c0+0,isf), 0.f));
    o.y = f2b(fmaxf(acc[1]/dhv + ldf(b2,c0+1,isf), 0.f));
    o.z = f2b(fmaxf(acc[2]/dhv + ldf(b2,c0+2,isf), 0.f));
    o.w = f2b(fmaxf(acc[3]/dhv + ldf(b2,c0+3,isf), 0.f));
    *(ushort4*)&hbf[(size_t)n*HC2 + c0] = o;  // == [b][i*1024+c] since n = b*1024+i
}

// ---------- split-K GEMV: out[b][c] += sum_k h[b][k]*W[k][c] ----------
template<int COLS>
__global__ __launch_bounds__(256) void k_gemv(const void* __restrict__ W,
        const u16* __restrict__ hbf, float* out, const int* flags){
    int isf = flags[0];
    const int GR    = COLS/8;
    const int KSTEP = 64/GR;
    int nwaves = gridDim.x*4;
    int KW   = DTOT/nwaves;
    int wid  = (blockIdx.x*256 + threadIdx.x) >> 6;
    int lane = threadIdx.x & 63;
    int kbase = wid*KW;
    int cg  = (lane % GR)*8;
    int kof = lane / GR;
    float acc[8][8];
    #pragma unroll
    for(int b=0;b<8;b++)
        #pragma unroll
        for(int c=0;c<8;c++) acc[b][c]=0.f;
    for(int it=0; it<KW/KSTEP; it++){
        int k = kbase + it*KSTEP + kof;
        float wv[8];
        if(isf){
            float4 wa = *(const float4*)((const float*)W + (size_t)k*COLS + cg);
            float4 wb = *(const float4*)((const float*)W + (size_t)k*COLS + cg + 4);
            wv[0]=wa.x;wv[1]=wa.y;wv[2]=wa.z;wv[3]=wa.w;
            wv[4]=wb.x;wv[5]=wb.y;wv[6]=wb.z;wv[7]=wb.w;
        } else {
            ushort4 wa = *(const ushort4*)((const u16*)W + (size_t)k*COLS + cg);
            ushort4 wb = *(const ushort4*)((const u16*)W + (size_t)k*COLS + cg + 4);
            wv[0]=b2f(wa.x);wv[1]=b2f(wa.y);wv[2]=b2f(wa.z);wv[3]=b2f(wa.w);
            wv[4]=b2f(wb.x);wv[5]=b2f(wb.y);wv[6]=b2f(wb.z);wv[7]=b2f(wb.w);
        }
        float hv[8];
        #pragma unroll
        for(int b=0;b<8;b++) hv[b] = b2f(hbf[(size_t)b*DTOT + k]);
        #pragma unroll
        for(int b=0;b<8;b++)
            #pragma unroll
            for(int c=0;c<8;c++) acc[b][c] += hv[b]*wv[c];
    }
    for(int m=GR;m<64;m<<=1){
        #pragma unroll
        for(int b=0;b<8;b++)
            #pragma unroll
            for(int c=0;c<8;c++) acc[b][c] += __shfl_xor(acc[b][c], m);
    }
    if(lane < GR){
        #pragma unroll
        for(int b=0;b<8;b++)
            #pragma unroll
            for(int c=0;c<8;c++) atomicAdd(&out[b*COLS + cg + c], acc[b][c]);
    }
}

// ---------- value MLP + dueling combine ----------
__global__ __launch_bounds__(512) void k_final(const float* __restrict__ v1a, const float* __restrict__ adva,
        const void* __restrict__ v1b, const void* __restrict__ advb,
        const void* __restrict__ w2v, const void* __restrict__ b2v,
        const void* __restrict__ w3v, const void* __restrict__ b3v,
        void* out, const int* flags){
    int isf = flags[0];
    __shared__ float v1[8][64], v2[8][64], adv[128], v3[8];
    int t = threadIdx.x;
    { int b=t>>6, j=t&63; v1[b][j] = fmaxf(v1a[t] + ldf(v1b,j,isf), 0.f); }
    if(t<128) adv[t] = fmaxf(adva[t] + ldf(advb,t&15,isf), 0.f);
    __syncthreads();
    { int b=t>>6, j=t&63;
      float a=0.f;
      for(int k=0;k<64;k++) a += v1[b][k]*ldf(w2v,k*64+j,isf);
      v2[b][j] = fmaxf(a + ldf(b2v,j,isf), 0.f); }
    __syncthreads();
    if(t<8){
        float a=0.f;
        for(int k=0;k<64;k++) a += v2[t][k]*ldf(w3v,k,isf);
        v3[t] = a + ldf(b3v,0,isf);
    }
    __syncthreads();
    if(t<128){
        int b=t>>4, r=(t>>2)&3;
        int base = b*16 + r*4;
        float m = 0.25f*(adv[base]+adv[base+1]+adv[base+2]+adv[base+3]);
        float val = v3[b] + adv[t] - m;
        if(isf) ((float*)out)[t] = val;
        else    ((u16*)out)[t]   = f2b(val);
    }
}

// ---------- host ----------
extern "C" void kernel_launch(void* const* d_in, const int* in_sizes, int n_in,
                              void* d_out, int out_size, void* d_ws, size_t ws_size,
                              hipStream_t stream){
    const void* x    = d_in[0];
    const int*  edge = (const int*)d_in[1];
    const int E = in_sizes[1]/2;
    const void* W1   = d_in[2];
    const void* as1w = d_in[3];
    const void* ad1w = d_in[4];
    const void* b1   = d_in[5];
    const void* W2   = d_in[6];
    const void* as2w = d_in[7];
    const void* ad2w = d_in[8];
    const void* b2   = d_in[9];
    const void* advw = d_in[10];
    const void* advb = d_in[11];
    const void* v1w  = d_in[12];
    const void* v1b  = d_in[13];
    const void* v2w  = d_in[14];
    const void* v2b  = d_in[15];
    const void* v3w  = d_in[16];
    const void* v3b  = d_in[17];

    char* wsp = (char*)d_ws;
    size_t o = 0;
    auto alloc = [&](size_t bytes)->char*{
        char* p = wsp + o;
        o = (o + bytes + 255) & ~(size_t)255;
        return p;
    };
    int*   flags  = (int*)  alloc(256);
    int*   counts = (int*)  alloc(NODES*4);
    int*   offs   = (int*)  alloc((NODES+8)*4);
    int*   cursor = (int*)  alloc(NODES*4);
    int*   csr    = (int*)  alloc((size_t)E*4);
    float* g1     = (float*)alloc((size_t)NODES*HC1*4);
    float* as1    = (float*)alloc((size_t)NODES*8*4);
    float* ad1    = (float*)alloc((size_t)NODES*8*4);
    float* z1     = (float*)alloc((size_t)NODES*HC1*4);
    u16*   g2     = (u16*)  alloc((size_t)NODES*HC2*2);
    float* as2    = (float*)alloc((size_t)NODES*8*4);
    float* ad2    = (float*)alloc((size_t)NODES*8*4);
    u16*   hbf    = (u16*)  alloc((size_t)NODES*HC2*2);
    float* v1a    = (float*)alloc(512*4);
    float* adva   = (float*)alloc(128*4);

    k_detect<<<1, 256, 0, stream>>>((const u16*)x, edge, flags);
    k_zero  <<<32, 256, 0, stream>>>(counts, v1a, adva);
    k_count <<<(E+255)/256, 256, 0, stream>>>(edge, E, counts, flags);
    k_scan  <<<1, 1024, 0, stream>>>(counts, offs, cursor);
    k_fill  <<<(E+255)/256, 256, 0, stream>>>(edge, E, cursor, csr, flags);
    k_dense1<<<NODES/4, 256, 0, stream>>>(x, W1, as1w, ad1w, g1, as1, ad1, flags);
    k_agg1  <<<NODES, 64, 0, stream>>>(offs, csr, g1, as1, ad1, b1, z1, flags);
    k_dense2<<<NODES/8, 256, 0, stream>>>(z1, W2, g2, flags);
    k_alpha2<<<NODES, 256, 0, stream>>>(g2, as2w, ad2w, as2, ad2, flags);
    k_agg2  <<<NODES, 256, 0, stream>>>(offs, csr, g2, as2, ad2, b2, hbf, flags);
    k_gemv<64><<<512, 256, 0, stream>>>(v1w, hbf, v1a, flags);
    k_gemv<16><<<512, 256, 0, stream>>>(advw, hbf, adva, flags);
    k_final <<<1, 512, 0, stream>>>(v1a, adva, v1b, advb, v2w, v2b, v3w, v3b, d_out, flags);
}

// Round 3
// 720.606 us; speedup vs baseline: 2.0126x; 2.0126x over previous
//
#include <hip/hip_runtime.h>
#include <stdint.h>

#define NODES   8192
#define BATCH   8
#define FIN     16
#define HC1     64
#define HC2     1024
#define DTOT    1048576
#define NEG     0.2f

typedef unsigned short u16;

__device__ __forceinline__ float b2f(u16 s){ return __uint_as_float(((unsigned)s)<<16); }
__device__ __forceinline__ u16 f2b(float f){
    unsigned u = __float_as_uint(f);
    unsigned r = u + 0x7fffu + ((u>>16)&1u);
    return (u16)(r>>16);
}
__device__ __forceinline__ float lrelu(float x){ return x > 0.f ? x : NEG*x; }
__device__ __forceinline__ float ldf(const void* p, long i, int isf){
    return isf ? ((const float*)p)[i] : b2f(((const u16*)p)[i]);
}

// ---------- dtype detector (fp32 vs bf16 floats; i64 vs i32 edges) ----------
__global__ void k_detect(const u16* __restrict__ xs, const int* __restrict__ ed, int* flags){
    __shared__ int cnt[2];
    int t = threadIdx.x;
    if(t<2) cnt[t]=0;
    __syncthreads();
    int bad=0;
    for(int i=t;i<1024;i+=256){
        u16 u = xs[i];
        float a = fabsf(b2f(u));
        if(!(u==0 || (a>1e-8f && a<1e4f))) bad++;
    }
    if(bad) atomicAdd(&cnt[0], bad);
    int z=0;
    for(int i=t;i<1024;i+=256){
        if(ed[2*i+1]==0) z++;
    }
    if(z) atomicAdd(&cnt[1], z);
    __syncthreads();
    if(t==0){ flags[0] = (cnt[0] > 64) ? 1 : 0; flags[1] = (cnt[1] > 512) ? 1 : 0; }
}

__device__ __forceinline__ int esrc(const int* e, int i, int i64){ return i64 ? e[2*i] : e[i]; }
__device__ __forceinline__ int edst(const int* e, int i, int E, int i64){ return i64 ? e[2*(E+i)] : e[E+i]; }

// ---------- zero counts ----------
__global__ void k_zero(int* counts){
    int i = blockIdx.x*256 + threadIdx.x;
    if(i < NODES) counts[i] = 0;
}

// ---------- degree count ----------
__global__ void k_count(const int* __restrict__ ed, int E, int* counts, const int* flags){
    int i64 = flags[1];
    int e = blockIdx.x*256 + threadIdx.x;
    if(e < E) atomicAdd(&counts[edst(ed,e,E,i64)], 1);
}

// ---------- exclusive scan ----------
__global__ __launch_bounds__(1024) void k_scan(const int* __restrict__ counts, int* offs, int* cursor){
    __shared__ int sums[1024];
    int t = threadIdx.x;
    int base = t*8;
    int loc[8]; int s = 0;
    for(int k=0;k<8;k++){ loc[k] = s; s += counts[base+k]; }
    sums[t] = s;
    __syncthreads();
    for(int off=1; off<1024; off<<=1){
        int v = (t>=off) ? sums[t-off] : 0;
        __syncthreads();
        sums[t] += v;
        __syncthreads();
    }
    int b = (t==0) ? 0 : sums[t-1];
    for(int k=0;k<8;k++){ int v = b + loc[k]; offs[base+k]=v; cursor[base+k]=v; }
    if(t==1023) offs[NODES] = sums[1023];
}

// ---------- CSR fill ----------
__global__ void k_fill(const int* __restrict__ ed, int E, int* cursor, int* csr, const int* flags){
    int i64 = flags[1];
    int e = blockIdx.x*256 + threadIdx.x;
    if(e < E){ int p = atomicAdd(&cursor[edst(ed,e,E,i64)], 1); csr[p] = esrc(ed,e,i64); }
}

// ---------- dense1 ----------
__global__ __launch_bounds__(256) void k_dense1(const void* __restrict__ x,
        const void* __restrict__ W1, const void* __restrict__ asw, const void* __restrict__ adw,
        float* g1, float* as1, float* ad1, const int* flags){
    int isf = flags[0];
    __shared__ float w1[FIN*HC1];
    __shared__ float av[64], dv[64];
    __shared__ float xr[4][FIN];
    __shared__ float hrow[4][HC1];
    int t = threadIdx.x;
    int n0 = blockIdx.x*4;
    for(int i=t;i<FIN*HC1;i+=256) w1[i] = ldf(W1,i,isf);
    if(t<64){ av[t]=ldf(asw,t,isf); dv[t]=ldf(adw,t,isf); }
    if(t<64) xr[t>>4][t&15] = ldf(x, n0*FIN + t, isf);
    __syncthreads();
    int i = t>>6, c = t&63;
    float acc = 0.f;
    #pragma unroll
    for(int k=0;k<FIN;k++) acc += xr[i][k]*w1[k*HC1+c];
    g1[(n0+i)*HC1 + c] = acc;
    hrow[i][c] = acc;
    __syncthreads();
    if(t<32){
        int ii=t>>3, h=t&7;
        float sa=0.f, sd=0.f;
        #pragma unroll
        for(int k=0;k<8;k++){ float v=hrow[ii][h*8+k]; sa+=v*av[h*8+k]; sd+=v*dv[h*8+k]; }
        as1[(n0+ii)*8+h]=sa; ad1[(n0+ii)*8+h]=sd;
    }
}

// ---------- conv1 aggregation (64 thr/node, parallel online softmax) ----------
__global__ __launch_bounds__(64) void k_agg1(const int* __restrict__ offs, const int* __restrict__ csr,
        const float* __restrict__ g1, const float* __restrict__ as1, const float* __restrict__ ad1,
        const void* __restrict__ b1, float* z1, const int* flags){
    int isf = flags[0];
    __shared__ float redm[64], redd[64];
    __shared__ float mh[8], dh[8], adl[8];
    __shared__ int src_l[64];
    __shared__ float wx[64*8];
    int n = blockIdx.x, t = threadIdx.x;
    int off = offs[n], deg = offs[n+1]-off, tot = deg+1;
    if(t<8) adl[t] = ad1[n*8+t];
    __syncthreads();
    {
        int h = t&7, jg = t>>3;
        float ad = adl[h];
        float m = -1e30f, d = 0.f;
        for(int j=jg; j<tot; j+=8){
            int s = (j<deg)?csr[off+j]:n;
            float e = lrelu(as1[s*8+h] + ad);
            if(e>m){ d = d*__expf(m-e) + 1.f; m = e; } else d += __expf(e-m);
        }
        redm[t]=m; redd[t]=d;
        __syncthreads();
        for(int st=4; st>=1; st>>=1){
            if(jg < st){
                float m2 = redm[t + st*8], d2 = redd[t + st*8];
                float mm = fmaxf(m, m2);
                d = d*__expf(m-mm) + d2*__expf(m2-mm);
                m = mm;
                redm[t]=m; redd[t]=d;
            }
            __syncthreads();
        }
        if(t<8){ mh[t]=redm[t]; dh[t]=redd[t] + 1e-16f; }
        __syncthreads();
    }
    int c = t, hc = t>>3;
    float acc = 0.f;
    for(int c0=0;c0<tot;c0+=64){
        int nc = min(64, tot-c0);
        if(t<nc){ int j=c0+t; src_l[t]=(j<deg)?csr[off+j]:n; }
        __syncthreads();
        for(int p=t;p<nc*8;p+=64){
            int j=p>>3, hh=p&7;
            float e = lrelu(as1[src_l[j]*8+hh] + adl[hh]);
            wx[p] = __expf(e - mh[hh]);
        }
        __syncthreads();
        for(int j=0;j<nc;j++) acc += wx[j*8+hc]*g1[src_l[j]*HC1 + c];
        __syncthreads();
    }
    z1[n*HC1 + c] = fmaxf(acc/dh[hc] + ldf(b1,c,isf), 0.f);
}

// ---------- dense2 ----------
__global__ __launch_bounds__(256) void k_dense2(const float* __restrict__ z1,
        const void* __restrict__ W2, u16* g2, const int* flags){
    int isf = flags[0];
    __shared__ float zr[8][HC1];
    int t = threadIdx.x;
    int n0 = blockIdx.x*8;
    for(int i=t;i<8*HC1;i+=256) zr[i>>6][i&63] = z1[n0*HC1 + i];
    __syncthreads();
    int c0 = t*4;
    float acc[8][4];
    #pragma unroll
    for(int i=0;i<8;i++){ acc[i][0]=0;acc[i][1]=0;acc[i][2]=0;acc[i][3]=0; }
    for(int k=0;k<HC1;k++){
        float w0,w1,w2,w3;
        if(isf){
            float4 w = *(const float4*)((const float*)W2 + (size_t)k*HC2 + c0);
            w0=w.x; w1=w.y; w2=w.z; w3=w.w;
        } else {
            ushort4 w = *(const ushort4*)((const u16*)W2 + (size_t)k*HC2 + c0);
            w0=b2f(w.x); w1=b2f(w.y); w2=b2f(w.z); w3=b2f(w.w);
        }
        #pragma unroll
        for(int i=0;i<8;i++){
            float zv = zr[i][k];
            acc[i][0]+=zv*w0; acc[i][1]+=zv*w1; acc[i][2]+=zv*w2; acc[i][3]+=zv*w3;
        }
    }
    #pragma unroll
    for(int i=0;i<8;i++){
        ushort4 o;
        o.x=f2b(acc[i][0]); o.y=f2b(acc[i][1]); o.z=f2b(acc[i][2]); o.w=f2b(acc[i][3]);
        *(ushort4*)&g2[(size_t)(n0+i)*HC2 + c0] = o;
    }
}

// ---------- alpha2 ----------
__global__ __launch_bounds__(256) void k_alpha2(const u16* __restrict__ g2,
        const void* __restrict__ asw, const void* __restrict__ adw,
        float* as2, float* ad2, const int* flags){
    int isf = flags[0];
    int n = blockIdx.x, t = threadIdx.x;
    int h = t>>5, l = t&31;
    int c = h*128 + l*4;
    ushort4 gv = *(const ushort4*)&g2[(size_t)n*HC2 + c];
    float s0,s1,s2,s3,d0,d1,d2,d3;
    if(isf){
        float4 sv = *(const float4*)((const float*)asw + c);
        float4 dv = *(const float4*)((const float*)adw + c);
        s0=sv.x;s1=sv.y;s2=sv.z;s3=sv.w; d0=dv.x;d1=dv.y;d2=dv.z;d3=dv.w;
    } else {
        ushort4 sv = *(const ushort4*)((const u16*)asw + c);
        ushort4 dv = *(const ushort4*)((const u16*)adw + c);
        s0=b2f(sv.x);s1=b2f(sv.y);s2=b2f(sv.z);s3=b2f(sv.w);
        d0=b2f(dv.x);d1=b2f(dv.y);d2=b2f(dv.z);d3=b2f(dv.w);
    }
    float g0=b2f(gv.x), g1v=b2f(gv.y), g2v=b2f(gv.z), g3=b2f(gv.w);
    float sa = g0*s0+g1v*s1+g2v*s2+g3*s3;
    float sd = g0*d0+g1v*d1+g2v*d2+g3*d3;
    for(int m=1;m<32;m<<=1){ sa += __shfl_xor(sa,m); sd += __shfl_xor(sd,m); }
    if(l==0){ as2[n*8+h]=sa; ad2[n*8+h]=sd; }
}

// ---------- conv2 aggregation (256 thr/node, parallel online softmax) ----------
__global__ __launch_bounds__(256) void k_agg2(const int* __restrict__ offs, const int* __restrict__ csr,
        const u16* __restrict__ g2, const float* __restrict__ as2, const float* __restrict__ ad2,
        const void* __restrict__ b2, u16* hbf, const int* flags){
    int isf = flags[0];
    __shared__ float redm[256], redd[256];
    __shared__ float mh[8], dh[8], adl[8];
    __shared__ int src_l[64];
    __shared__ float wx[64*8];
    int n = blockIdx.x, t = threadIdx.x;
    int off = offs[n], deg = offs[n+1]-off, tot = deg+1;
    if(t<8) adl[t] = ad2[n*8+t];
    __syncthreads();
    {
        int h = t&7, jg = t>>3;
        float ad = adl[h];
        float m = -1e30f, d = 0.f;
        for(int j=jg; j<tot; j+=32){
            int s = (j<deg)?csr[off+j]:n;
            float e = lrelu(as2[s*8+h] + ad);
            if(e>m){ d = d*__expf(m-e) + 1.f; m = e; } else d += __expf(e-m);
        }
        redm[t]=m; redd[t]=d;
        __syncthreads();
        for(int st=16; st>=1; st>>=1){
            if(jg < st){
                float m2 = redm[t + st*8], d2 = redd[t + st*8];
                float mm = fmaxf(m, m2);
                d = d*__expf(m-mm) + d2*__expf(m2-mm);
                m = mm;
                redm[t]=m; redd[t]=d;
            }
            __syncthreads();
        }
        if(t<8){ mh[t]=redm[t]; dh[t]=redd[t] + 1e-16f; }
        __syncthreads();
    }
    int c0 = t*4, hc = t>>5;
    float acc[4] = {0,0,0,0};
    for(int cc0=0;cc0<tot;cc0+=64){
        int nc = min(64, tot-cc0);
        if(t<nc){ int j=cc0+t; src_l[t]=(j<deg)?csr[off+j]:n; }
        __syncthreads();
        for(int p=t;p<nc*8;p+=256){
            int j=p>>3, hh=p&7;
            float e = lrelu(as2[src_l[j]*8+hh] + adl[hh]);
            wx[p] = __expf(e - mh[hh]);
        }
        __syncthreads();
        for(int j=0;j<nc;j++){
            float w = wx[j*8+hc];
            ushort4 gv = *(const ushort4*)&g2[(size_t)src_l[j]*HC2 + c0];
            acc[0]+=w*b2f(gv.x); acc[1]+=w*b2f(gv.y); acc[2]+=w*b2f(gv.z); acc[3]+=w*b2f(gv.w);
        }
        __syncthreads();
    }
    float dhv = dh[hc];
    ushort4 o;
    o.x = f2b(fmaxf(acc[0]/dhv + ldf(b2,c0+0,isf), 0.f));
    o.y = f2b(fmaxf(acc[1]/dhv + ldf(b2,c0+1,isf), 0.f));
    o.z = f2b(fmaxf(acc[2]/dhv + ldf(b2,c0+2,isf), 0.f));
    o.w = f2b(fmaxf(acc[3]/dhv + ldf(b2,c0+3,isf), 0.f));
    *(ushort4*)&hbf[(size_t)n*HC2 + c0] = o;
}

// ---------- fused head GEMVs ----------
template<int COLS, int NW>
__device__ __forceinline__ void gemv_part(const void* __restrict__ W, const u16* __restrict__ hbf,
        float* __restrict__ scratch, int wid, int lane, int isf){
    const int GR    = COLS/8;
    const int KSTEP = 64/GR;
    const int ITERS = DTOT/(NW*KSTEP);
    int cg  = (lane % GR)*8;
    int kof = lane / GR;
    float acc[8][8];
    #pragma unroll
    for(int b=0;b<8;b++)
        #pragma unroll
        for(int c=0;c<8;c++) acc[b][c]=0.f;
    for(int it=0; it<ITERS; it++){
        int k = (it*NW + wid)*KSTEP + kof;
        float wv[8];
        if(isf){
            float4 wa = *(const float4*)((const float*)W + (size_t)k*COLS + cg);
            float4 wb = *(const float4*)((const float*)W + (size_t)k*COLS + cg + 4);
            wv[0]=wa.x;wv[1]=wa.y;wv[2]=wa.z;wv[3]=wa.w;
            wv[4]=wb.x;wv[5]=wb.y;wv[6]=wb.z;wv[7]=wb.w;
        } else {
            ushort4 wa = *(const ushort4*)((const u16*)W + (size_t)k*COLS + cg);
            ushort4 wb = *(const ushort4*)((const u16*)W + (size_t)k*COLS + cg + 4);
            wv[0]=b2f(wa.x);wv[1]=b2f(wa.y);wv[2]=b2f(wa.z);wv[3]=b2f(wa.w);
            wv[4]=b2f(wb.x);wv[5]=b2f(wb.y);wv[6]=b2f(wb.z);wv[7]=b2f(wb.w);
        }
        float hv[8];
        #pragma unroll
        for(int b=0;b<8;b++) hv[b] = b2f(hbf[(size_t)b*DTOT + k]);
        #pragma unroll
        for(int b=0;b<8;b++)
            #pragma unroll
            for(int c=0;c<8;c++) acc[b][c] += hv[b]*wv[c];
    }
    #pragma unroll
    for(int m=GR;m<64;m<<=1){
        #pragma unroll
        for(int b=0;b<8;b++)
            #pragma unroll
            for(int c=0;c<8;c++) acc[b][c] += __shfl_xor(acc[b][c], m);
    }
    int q = lane / GR;
    if(q < 8){
        float4 o0, o1;
        o0.x=acc[q][0]; o0.y=acc[q][1]; o0.z=acc[q][2]; o0.w=acc[q][3];
        o1.x=acc[q][4]; o1.y=acc[q][5]; o1.z=acc[q][6]; o1.w=acc[q][7];
        float* dst = scratch + (size_t)wid*COLS*8 + q*COLS + cg;
        *(float4*)dst       = o0;
        *(float4*)(dst + 4) = o1;
    }
}

__global__ __launch_bounds__(256) void k_heads(const void* __restrict__ v1w, const void* __restrict__ advw,
        const u16* __restrict__ hbf, float* s1, float* s2, const int* flags){
    int isf = flags[0];
    int lane = threadIdx.x & 63;
    if(blockIdx.x < 512){
        int wid = (int)((blockIdx.x*256 + threadIdx.x) >> 6);
        gemv_part<64,2048>(v1w, hbf, s1, wid, lane, isf);
    } else {
        int wid = (int)(((blockIdx.x-512)*256 + threadIdx.x) >> 6);
        gemv_part<16,512>(advw, hbf, s2, wid, lane, isf);
    }
}

// ---------- reduce partials ----------
__global__ __launch_bounds__(256) void k_reduce(const float* __restrict__ s1, const float* __restrict__ s2,
        float* v1a, float* adva){
    __shared__ float red[256];
    int blk = blockIdx.x, t = threadIdx.x;
    if(blk < 8){
        int o = blk*64 + (t&63);
        float a = 0.f;
        for(int p = (t>>6); p < 2048; p += 4) a += s1[(size_t)p*512 + o];
        red[t] = a; __syncthreads();
        if(t<64) v1a[o] = red[t]+red[t+64]+red[t+128]+red[t+192];
    } else {
        int o = (blk-8)*64 + (t&63);
        float a = 0.f;
        for(int p = (t>>6); p < 512; p += 4) a += s2[(size_t)p*128 + o];
        red[t] = a; __syncthreads();
        if(t<64) adva[o] = red[t]+red[t+64]+red[t+128]+red[t+192];
    }
}

// ---------- value MLP + dueling combine ----------
__global__ __launch_bounds__(512) void k_final(const float* __restrict__ v1a, const float* __restrict__ adva,
        const void* __restrict__ v1b, const void* __restrict__ advb,
        const void* __restrict__ w2v, const void* __restrict__ b2v,
        const void* __restrict__ w3v, const void* __restrict__ b3v,
        void* out, const int* flags){
    int isf = flags[0];
    __shared__ float v1[8][64], v2[8][64], adv[128], v3[8];
    int t = threadIdx.x;
    { int b=t>>6, j=t&63; v1[b][j] = fmaxf(v1a[t] + ldf(v1b,j,isf), 0.f); }
    if(t<128) adv[t] = fmaxf(adva[t] + ldf(advb,t&15,isf), 0.f);
    __syncthreads();
    { int b=t>>6, j=t&63;
      float a=0.f;
      for(int k=0;k<64;k++) a += v1[b][k]*ldf(w2v,k*64+j,isf);
      v2[b][j] = fmaxf(a + ldf(b2v,j,isf), 0.f); }
    __syncthreads();
    if(t<8){
        float a=0.f;
        for(int k=0;k<64;k++) a += v2[t][k]*ldf(w3v,k,isf);
        v3[t] = a + ldf(b3v,0,isf);
    }
    __syncthreads();
    if(t<128){
        int b=t>>4, r=(t>>2)&3;
        int base = b*16 + r*4;
        float m = 0.25f*(adv[base]+adv[base+1]+adv[base+2]+adv[base+3]);
        float val = v3[b] + adv[t] - m;
        if(isf) ((float*)out)[t] = val;
        else    ((u16*)out)[t]   = f2b(val);
    }
}

// ---------- host ----------
extern "C" void kernel_launch(void* const* d_in, const int* in_sizes, int n_in,
                              void* d_out, int out_size, void* d_ws, size_t ws_size,
                              hipStream_t stream){
    const void* x    = d_in[0];
    const int*  edge = (const int*)d_in[1];
    const int E = in_sizes[1]/2;
    const void* W1   = d_in[2];
    const void* as1w = d_in[3];
    const void* ad1w = d_in[4];
    const void* b1   = d_in[5];
    const void* W2   = d_in[6];
    const void* as2w = d_in[7];
    const void* ad2w = d_in[8];
    const void* b2   = d_in[9];
    const void* advw = d_in[10];
    const void* advb = d_in[11];
    const void* v1w  = d_in[12];
    const void* v1b  = d_in[13];
    const void* v2w  = d_in[14];
    const void* v2b  = d_in[15];
    const void* v3w  = d_in[16];
    const void* v3b  = d_in[17];

    char* wsp = (char*)d_ws;
    size_t o = 0;
    auto alloc = [&](size_t bytes)->char*{
        char* p = wsp + o;
        o = (o + bytes + 255) & ~(size_t)255;
        return p;
    };
    int*   flags  = (int*)  alloc(256);
    int*   counts = (int*)  alloc(NODES*4);
    int*   offs   = (int*)  alloc((NODES+8)*4);
    int*   cursor = (int*)  alloc(NODES*4);
    int*   csr    = (int*)  alloc((size_t)E*4);
    float* g1     = (float*)alloc((size_t)NODES*HC1*4);
    float* as1    = (float*)alloc((size_t)NODES*8*4);
    float* ad1    = (float*)alloc((size_t)NODES*8*4);
    float* z1     = (float*)alloc((size_t)NODES*HC1*4);
    u16*   g2     = (u16*)  alloc((size_t)NODES*HC2*2);
    float* as2    = (float*)alloc((size_t)NODES*8*4);
    float* ad2    = (float*)alloc((size_t)NODES*8*4);
    u16*   hbf    = (u16*)  alloc((size_t)NODES*HC2*2);
    float* s1     = (float*)alloc((size_t)2048*512*4);
    float* s2     = (float*)alloc((size_t)512*128*4);
    float* v1a    = (float*)alloc(512*4);
    float* adva   = (float*)alloc(128*4);

    k_detect<<<1, 256, 0, stream>>>((const u16*)x, edge, flags);
    k_zero  <<<32, 256, 0, stream>>>(counts);
    k_count <<<(E+255)/256, 256, 0, stream>>>(edge, E, counts, flags);
    k_scan  <<<1, 1024, 0, stream>>>(counts, offs, cursor);
    k_fill  <<<(E+255)/256, 256, 0, stream>>>(edge, E, cursor, csr, flags);
    k_dense1<<<NODES/4, 256, 0, stream>>>(x, W1, as1w, ad1w, g1, as1, ad1, flags);
    k_agg1  <<<NODES, 64, 0, stream>>>(offs, csr, g1, as1, ad1, b1, z1, flags);
    k_dense2<<<NODES/8, 256, 0, stream>>>(z1, W2, g2, flags);
    k_alpha2<<<NODES, 256, 0, stream>>>(g2, as2w, ad2w, as2, ad2, flags);
    k_agg2  <<<NODES, 256, 0, stream>>>(offs, csr, g2, as2, ad2, b2, hbf, flags);
    k_heads <<<640, 256, 0, stream>>>(v1w, advw, hbf, s1, s2, flags);
    k_reduce<<<10, 256, 0, stream>>>(s1, s2, v1a, adva);
    k_final <<<1, 512, 0, stream>>>(v1a, adva, v1b, advb, v2w, v2b, v3w, v3b, d_out, flags);
}

// Round 4
// 681.383 us; speedup vs baseline: 2.1284x; 1.0576x over previous
//
#include <hip/hip_runtime.h>
#include <stdint.h>

#define NODES   8192
#define BATCH   8
#define FIN     16
#define HC1     64
#define HC2     1024
#define DTOT    1048576
#define NEG     0.2f

typedef unsigned short u16;

__device__ __forceinline__ float b2f(u16 s){ return __uint_as_float(((unsigned)s)<<16); }
__device__ __forceinline__ u16 f2b(float f){
    unsigned u = __float_as_uint(f);
    unsigned r = u + 0x7fffu + ((u>>16)&1u);
    return (u16)(r>>16);
}
__device__ __forceinline__ float lrelu(float x){ return x > 0.f ? x : NEG*x; }
__device__ __forceinline__ float ldf(const void* p, long i, int isf){
    return isf ? ((const float*)p)[i] : b2f(((const u16*)p)[i]);
}

__device__ __forceinline__ int esrc(const int* e, int i, int i64){ return i64 ? e[2*i] : e[i]; }
__device__ __forceinline__ int edst(const int* e, int i, int E, int i64){ return i64 ? e[2*(E+i)] : e[E+i]; }

// ---------- prep: dtype detect (block 0) + zero counts (blocks 1..32) ----------
__global__ __launch_bounds__(256) void k_prep(const u16* __restrict__ xs, const int* __restrict__ ed,
        int* flags, int* counts){
    int t = threadIdx.x;
    if(blockIdx.x == 0){
        __shared__ int cnt[2];
        if(t<2) cnt[t]=0;
        __syncthreads();
        int bad=0;
        for(int i=t;i<1024;i+=256){
            u16 u = xs[i];
            float a = fabsf(b2f(u));
            if(!(u==0 || (a>1e-8f && a<1e4f))) bad++;
        }
        if(bad) atomicAdd(&cnt[0], bad);
        int z=0;
        for(int i=t;i<1024;i+=256){
            if(ed[2*i+1]==0) z++;
        }
        if(z) atomicAdd(&cnt[1], z);
        __syncthreads();
        if(t==0){ flags[0] = (cnt[0] > 64) ? 1 : 0; flags[1] = (cnt[1] > 512) ? 1 : 0; }
    } else {
        int i = (blockIdx.x-1)*256 + t;
        if(i < NODES) counts[i] = 0;
    }
}

// ---------- count (blocks 0..511)  ||  dense1 (blocks 512..2559) ----------
__global__ __launch_bounds__(256) void k_cnt_d1(const int* __restrict__ ed, int E, int* counts,
        const void* __restrict__ x, const void* __restrict__ W1,
        const void* __restrict__ asw, const void* __restrict__ adw,
        float* g1, float* as1, float* ad1, const int* flags){
    int t = threadIdx.x;
    if(blockIdx.x < 512){
        int i64 = flags[1];
        int e = blockIdx.x*256 + t;
        if(e < E) atomicAdd(&counts[edst(ed,e,E,i64)], 1);
        return;
    }
    int isf = flags[0];
    __shared__ float w1[FIN*HC1];
    __shared__ float av[64], dv[64];
    __shared__ float xr[4][FIN];
    __shared__ float hrow[4][HC1];
    int n0 = (blockIdx.x-512)*4;
    for(int i=t;i<FIN*HC1;i+=256) w1[i] = ldf(W1,i,isf);
    if(t<64){ av[t]=ldf(asw,t,isf); dv[t]=ldf(adw,t,isf); }
    if(t<64) xr[t>>4][t&15] = ldf(x, n0*FIN + t, isf);
    __syncthreads();
    int i = t>>6, c = t&63;
    float acc = 0.f;
    #pragma unroll
    for(int k=0;k<FIN;k++) acc += xr[i][k]*w1[k*HC1+c];
    g1[(n0+i)*HC1 + c] = acc;
    hrow[i][c] = acc;
    __syncthreads();
    if(t<32){
        int ii=t>>3, h=t&7;
        float sa=0.f, sd=0.f;
        #pragma unroll
        for(int k=0;k<8;k++){ float v=hrow[ii][h*8+k]; sa+=v*av[h*8+k]; sd+=v*dv[h*8+k]; }
        as1[(n0+ii)*8+h]=sa; ad1[(n0+ii)*8+h]=sd;
    }
}

// ---------- exclusive scan ----------
__global__ __launch_bounds__(1024) void k_scan(const int* __restrict__ counts, int* offs, int* cursor){
    __shared__ int sums[1024];
    int t = threadIdx.x;
    int base = t*8;
    int loc[8]; int s = 0;
    for(int k=0;k<8;k++){ loc[k] = s; s += counts[base+k]; }
    sums[t] = s;
    __syncthreads();
    for(int off=1; off<1024; off<<=1){
        int v = (t>=off) ? sums[t-off] : 0;
        __syncthreads();
        sums[t] += v;
        __syncthreads();
    }
    int b = (t==0) ? 0 : sums[t-1];
    for(int k=0;k<8;k++){ int v = b + loc[k]; offs[base+k]=v; cursor[base+k]=v; }
    if(t==1023) offs[NODES] = sums[1023];
}

// ---------- CSR fill ----------
__global__ void k_fill(const int* __restrict__ ed, int E, int* cursor, int* csr, const int* flags){
    int i64 = flags[1];
    int e = blockIdx.x*256 + threadIdx.x;
    if(e < E){ int p = atomicAdd(&cursor[edst(ed,e,E,i64)], 1); csr[p] = esrc(ed,e,i64); }
}

// ---------- conv1 aggregation (64 thr/node) ----------
__global__ __launch_bounds__(64) void k_agg1(const int* __restrict__ offs, const int* __restrict__ csr,
        const float* __restrict__ g1, const float* __restrict__ as1, const float* __restrict__ ad1,
        const void* __restrict__ b1, float* z1, const int* flags){
    int isf = flags[0];
    __shared__ float redm[64], redd[64];
    __shared__ float mh[8], dh[8], adl[8];
    __shared__ int src_l[64];
    __shared__ float wx[64*8];
    int n = blockIdx.x, t = threadIdx.x;
    int off = offs[n], deg = offs[n+1]-off, tot = deg+1;
    if(t<8) adl[t] = ad1[n*8+t];
    __syncthreads();
    {
        int h = t&7, jg = t>>3;
        float ad = adl[h];
        float m = -1e30f, d = 0.f;
        for(int j=jg; j<tot; j+=8){
            int s = (j<deg)?csr[off+j]:n;
            float e = lrelu(as1[s*8+h] + ad);
            if(e>m){ d = d*__expf(m-e) + 1.f; m = e; } else d += __expf(e-m);
        }
        redm[t]=m; redd[t]=d;
        __syncthreads();
        for(int st=4; st>=1; st>>=1){
            if(jg < st){
                float m2 = redm[t + st*8], d2 = redd[t + st*8];
                float mm = fmaxf(m, m2);
                d = d*__expf(m-mm) + d2*__expf(m2-mm);
                m = mm;
                redm[t]=m; redd[t]=d;
            }
            __syncthreads();
        }
        if(t<8){ mh[t]=redm[t]; dh[t]=redd[t] + 1e-16f; }
        __syncthreads();
    }
    int c = t, hc = t>>3;
    float acc = 0.f;
    for(int c0=0;c0<tot;c0+=64){
        int nc = min(64, tot-c0);
        if(t<nc){ int j=c0+t; src_l[t]=(j<deg)?csr[off+j]:n; }
        __syncthreads();
        for(int p=t;p<nc*8;p+=64){
            int j=p>>3, hh=p&7;
            float e = lrelu(as1[src_l[j]*8+hh] + adl[hh]);
            wx[p] = __expf(e - mh[hh]);
        }
        __syncthreads();
        int j = 0;
        for(; j+2<=nc; j+=2){
            float w0 = wx[j*8+hc],     v0 = g1[src_l[j]*HC1 + c];
            float w1 = wx[(j+1)*8+hc], v1 = g1[src_l[j+1]*HC1 + c];
            acc += w0*v0 + w1*v1;
        }
        if(j<nc) acc += wx[j*8+hc]*g1[src_l[j]*HC1 + c];
        __syncthreads();
    }
    z1[n*HC1 + c] = fmaxf(acc/dh[hc] + ldf(b1,c,isf), 0.f);
}

// ---------- dense2 + alpha2 fused ----------
__global__ __launch_bounds__(256) void k_d2a2(const float* __restrict__ z1,
        const void* __restrict__ W2, const void* __restrict__ asw, const void* __restrict__ adw,
        u16* g2, float* as2, float* ad2, const int* flags){
    int isf = flags[0];
    __shared__ float zr[8][HC1];
    __shared__ float avs[HC2], ads[HC2];
    int t = threadIdx.x;
    int n0 = blockIdx.x*8;
    for(int i=t;i<8*HC1;i+=256) zr[i>>6][i&63] = z1[n0*HC1 + i];
    for(int i=t;i<HC2;i+=256){ avs[i]=ldf(asw,i,isf); ads[i]=ldf(adw,i,isf); }
    __syncthreads();
    int c0 = t*4;
    float acc[8][4];
    #pragma unroll
    for(int i=0;i<8;i++){ acc[i][0]=0;acc[i][1]=0;acc[i][2]=0;acc[i][3]=0; }
    for(int k=0;k<HC1;k++){
        float w0,w1,w2,w3;
        if(isf){
            float4 w = *(const float4*)((const float*)W2 + (size_t)k*HC2 + c0);
            w0=w.x; w1=w.y; w2=w.z; w3=w.w;
        } else {
            ushort4 w = *(const ushort4*)((const u16*)W2 + (size_t)k*HC2 + c0);
            w0=b2f(w.x); w1=b2f(w.y); w2=b2f(w.z); w3=b2f(w.w);
        }
        #pragma unroll
        for(int i=0;i<8;i++){
            float zv = zr[i][k];
            acc[i][0]+=zv*w0; acc[i][1]+=zv*w1; acc[i][2]+=zv*w2; acc[i][3]+=zv*w3;
        }
    }
    float a0=avs[c0], a1=avs[c0+1], a2=avs[c0+2], a3=avs[c0+3];
    float d0=ads[c0], d1=ads[c0+1], d2=ads[c0+2], d3=ads[c0+3];
    int h = t>>5;
    #pragma unroll
    for(int i=0;i<8;i++){
        ushort4 o;
        o.x=f2b(acc[i][0]); o.y=f2b(acc[i][1]); o.z=f2b(acc[i][2]); o.w=f2b(acc[i][3]);
        *(ushort4*)&g2[(size_t)(n0+i)*HC2 + c0] = o;
        float pa = acc[i][0]*a0 + acc[i][1]*a1 + acc[i][2]*a2 + acc[i][3]*a3;
        float pd = acc[i][0]*d0 + acc[i][1]*d1 + acc[i][2]*d2 + acc[i][3]*d3;
        #pragma unroll
        for(int m=1;m<32;m<<=1){ pa += __shfl_xor(pa,m); pd += __shfl_xor(pd,m); }
        if((t&31)==0){ as2[(n0+i)*8+h]=pa; ad2[(n0+i)*8+h]=pd; }
    }
}

// ---------- conv2 aggregation (256 thr/node) ----------
__global__ __launch_bounds__(256) void k_agg2(const int* __restrict__ offs, const int* __restrict__ csr,
        const u16* __restrict__ g2, const float* __restrict__ as2, const float* __restrict__ ad2,
        const void* __restrict__ b2, u16* hbf, const int* flags){
    int isf = flags[0];
    __shared__ float redm[256], redd[256];
    __shared__ float mh[8], dh[8], adl[8];
    __shared__ int src_l[64];
    __shared__ float wx[64*8];
    int n = blockIdx.x, t = threadIdx.x;
    int off = offs[n], deg = offs[n+1]-off, tot = deg+1;
    if(t<8) adl[t] = ad2[n*8+t];
    __syncthreads();
    {
        int h = t&7, jg = t>>3;
        float ad = adl[h];
        float m = -1e30f, d = 0.f;
        for(int j=jg; j<tot; j+=32){
            int s = (j<deg)?csr[off+j]:n;
            float e = lrelu(as2[s*8+h] + ad);
            if(e>m){ d = d*__expf(m-e) + 1.f; m = e; } else d += __expf(e-m);
        }
        redm[t]=m; redd[t]=d;
        __syncthreads();
        for(int st=16; st>=1; st>>=1){
            if(jg < st){
                float m2 = redm[t + st*8], d2 = redd[t + st*8];
                float mm = fmaxf(m, m2);
                d = d*__expf(m-mm) + d2*__expf(m2-mm);
                m = mm;
                redm[t]=m; redd[t]=d;
            }
            __syncthreads();
        }
        if(t<8){ mh[t]=redm[t]; dh[t]=redd[t] + 1e-16f; }
        __syncthreads();
    }
    int c0 = t*4, hc = t>>5;
    float acc[4] = {0,0,0,0};
    for(int cc0=0;cc0<tot;cc0+=64){
        int nc = min(64, tot-cc0);
        if(t<nc){ int j=cc0+t; src_l[t]=(j<deg)?csr[off+j]:n; }
        __syncthreads();
        for(int p=t;p<nc*8;p+=256){
            int j=p>>3, hh=p&7;
            float e = lrelu(as2[src_l[j]*8+hh] + adl[hh]);
            wx[p] = __expf(e - mh[hh]);
        }
        __syncthreads();
        int j = 0;
        for(; j+2<=nc; j+=2){
            float w0 = wx[j*8+hc], w1 = wx[(j+1)*8+hc];
            ushort4 gv0 = *(const ushort4*)&g2[(size_t)src_l[j]*HC2 + c0];
            ushort4 gv1 = *(const ushort4*)&g2[(size_t)src_l[j+1]*HC2 + c0];
            acc[0]+=w0*b2f(gv0.x)+w1*b2f(gv1.x);
            acc[1]+=w0*b2f(gv0.y)+w1*b2f(gv1.y);
            acc[2]+=w0*b2f(gv0.z)+w1*b2f(gv1.z);
            acc[3]+=w0*b2f(gv0.w)+w1*b2f(gv1.w);
        }
        if(j<nc){
            float w = wx[j*8+hc];
            ushort4 gv = *(const ushort4*)&g2[(size_t)src_l[j]*HC2 + c0];
            acc[0]+=w*b2f(gv.x); acc[1]+=w*b2f(gv.y); acc[2]+=w*b2f(gv.z); acc[3]+=w*b2f(gv.w);
        }
        __syncthreads();
    }
    float dhv = dh[hc];
    ushort4 o;
    o.x = f2b(fmaxf(acc[0]/dhv + ldf(b2,c0+0,isf), 0.f));
    o.y = f2b(fmaxf(acc[1]/dhv + ldf(b2,c0+1,isf), 0.f));
    o.z = f2b(fmaxf(acc[2]/dhv + ldf(b2,c0+2,isf), 0.f));
    o.w = f2b(fmaxf(acc[3]/dhv + ldf(b2,c0+3,isf), 0.f));
    *(ushort4*)&hbf[(size_t)n*HC2 + c0] = o;
}

// ---------- fused head GEMVs (unrolled x2) ----------
template<int COLS, int NW>
__device__ __forceinline__ void gemv_part(const void* __restrict__ W, const u16* __restrict__ hbf,
        float* __restrict__ scratch, int wid, int lane, int isf){
    const int GR    = COLS/8;
    const int KSTEP = 64/GR;
    const int ITERS = DTOT/(NW*KSTEP);
    int cg  = (lane % GR)*8;
    int kof = lane / GR;
    float acc[8][8];
    #pragma unroll
    for(int b=0;b<8;b++)
        #pragma unroll
        for(int c=0;c<8;c++) acc[b][c]=0.f;
    for(int it=0; it<ITERS; it+=2){
        int k0 = (it*NW + wid)*KSTEP + kof;
        int k1 = ((it+1)*NW + wid)*KSTEP + kof;
        float wv0[8], wv1[8];
        if(isf){
            float4 a0 = *(const float4*)((const float*)W + (size_t)k0*COLS + cg);
            float4 b0 = *(const float4*)((const float*)W + (size_t)k0*COLS + cg + 4);
            float4 a1 = *(const float4*)((const float*)W + (size_t)k1*COLS + cg);
            float4 b1 = *(const float4*)((const float*)W + (size_t)k1*COLS + cg + 4);
            wv0[0]=a0.x;wv0[1]=a0.y;wv0[2]=a0.z;wv0[3]=a0.w;wv0[4]=b0.x;wv0[5]=b0.y;wv0[6]=b0.z;wv0[7]=b0.w;
            wv1[0]=a1.x;wv1[1]=a1.y;wv1[2]=a1.z;wv1[3]=a1.w;wv1[4]=b1.x;wv1[5]=b1.y;wv1[6]=b1.z;wv1[7]=b1.w;
        } else {
            ushort4 a0 = *(const ushort4*)((const u16*)W + (size_t)k0*COLS + cg);
            ushort4 b0 = *(const ushort4*)((const u16*)W + (size_t)k0*COLS + cg + 4);
            ushort4 a1 = *(const ushort4*)((const u16*)W + (size_t)k1*COLS + cg);
            ushort4 b1 = *(const ushort4*)((const u16*)W + (size_t)k1*COLS + cg + 4);
            wv0[0]=b2f(a0.x);wv0[1]=b2f(a0.y);wv0[2]=b2f(a0.z);wv0[3]=b2f(a0.w);
            wv0[4]=b2f(b0.x);wv0[5]=b2f(b0.y);wv0[6]=b2f(b0.z);wv0[7]=b2f(b0.w);
            wv1[0]=b2f(a1.x);wv1[1]=b2f(a1.y);wv1[2]=b2f(a1.z);wv1[3]=b2f(a1.w);
            wv1[4]=b2f(b1.x);wv1[5]=b2f(b1.y);wv1[6]=b2f(b1.z);wv1[7]=b2f(b1.w);
        }
        float hv0[8], hv1[8];
        #pragma unroll
        for(int b=0;b<8;b++){ hv0[b] = b2f(hbf[(size_t)b*DTOT + k0]); hv1[b] = b2f(hbf[(size_t)b*DTOT + k1]); }
        #pragma unroll
        for(int b=0;b<8;b++)
            #pragma unroll
            for(int c=0;c<8;c++) acc[b][c] += hv0[b]*wv0[c] + hv1[b]*wv1[c];
    }
    #pragma unroll
    for(int m=GR;m<64;m<<=1){
        #pragma unroll
        for(int b=0;b<8;b++)
            #pragma unroll
            for(int c=0;c<8;c++) acc[b][c] += __shfl_xor(acc[b][c], m);
    }
    int q = lane / GR;
    if(q < 8){
        float4 o0, o1;
        o0.x=acc[q][0]; o0.y=acc[q][1]; o0.z=acc[q][2]; o0.w=acc[q][3];
        o1.x=acc[q][4]; o1.y=acc[q][5]; o1.z=acc[q][6]; o1.w=acc[q][7];
        float* dst = scratch + (size_t)wid*COLS*8 + q*COLS + cg;
        *(float4*)dst       = o0;
        *(float4*)(dst + 4) = o1;
    }
}

__global__ __launch_bounds__(256) void k_heads(const void* __restrict__ v1w, const void* __restrict__ advw,
        const u16* __restrict__ hbf, float* s1, float* s2, const int* flags){
    int isf = flags[0];
    int lane = threadIdx.x & 63;
    if(blockIdx.x < 1024){
        int wid = (int)((blockIdx.x*256 + threadIdx.x) >> 6);
        gemv_part<64,4096>(v1w, hbf, s1, wid, lane, isf);
    } else {
        int wid = (int)(((blockIdx.x-1024)*256 + threadIdx.x) >> 6);
        gemv_part<16,1024>(advw, hbf, s2, wid, lane, isf);
    }
}

// ---------- reduce partials ----------
__global__ __launch_bounds__(1024) void k_reduce(const float* __restrict__ s1, const float* __restrict__ s2,
        float* v1a, float* adva){
    __shared__ float red[1024];
    int blk = blockIdx.x, t = threadIdx.x;
    int ph = t>>6, ln = t&63;
    float a = 0.f;
    if(blk < 8){
        int o = blk*64 + ln;
        for(int p = ph; p < 4096; p += 16) a += s1[(size_t)p*512 + o];
        red[t] = a; __syncthreads();
        if(t<64){ float s=0.f; for(int q=0;q<16;q++) s += red[q*64+t]; v1a[blk*64+t]=s; }
    } else {
        int o = (blk-8)*64 + ln;
        for(int p = ph; p < 1024; p += 16) a += s2[(size_t)p*128 + o];
        red[t] = a; __syncthreads();
        if(t<64){ float s=0.f; for(int q=0;q<16;q++) s += red[q*64+t]; adva[(blk-8)*64+t]=s; }
    }
}

// ---------- value MLP + dueling combine ----------
__global__ __launch_bounds__(512) void k_final(const float* __restrict__ v1a, const float* __restrict__ adva,
        const void* __restrict__ v1b, const void* __restrict__ advb,
        const void* __restrict__ w2v, const void* __restrict__ b2v,
        const void* __restrict__ w3v, const void* __restrict__ b3v,
        void* out, const int* flags){
    int isf = flags[0];
    __shared__ float v1[8][64], v2[8][64], adv[128], v3[8];
    int t = threadIdx.x;
    { int b=t>>6, j=t&63; v1[b][j] = fmaxf(v1a[t] + ldf(v1b,j,isf), 0.f); }
    if(t<128) adv[t] = fmaxf(adva[t] + ldf(advb,t&15,isf), 0.f);
    __syncthreads();
    { int b=t>>6, j=t&63;
      float a=0.f;
      for(int k=0;k<64;k++) a += v1[b][k]*ldf(w2v,k*64+j,isf);
      v2[b][j] = fmaxf(a + ldf(b2v,j,isf), 0.f); }
    __syncthreads();
    if(t<8){
        float a=0.f;
        for(int k=0;k<64;k++) a += v2[t][k]*ldf(w3v,k,isf);
        v3[t] = a + ldf(b3v,0,isf);
    }
    __syncthreads();
    if(t<128){
        int b=t>>4, r=(t>>2)&3;
        int base = b*16 + r*4;
        float m = 0.25f*(adv[base]+adv[base+1]+adv[base+2]+adv[base+3]);
        float val = v3[b] + adv[t] - m;
        if(isf) ((float*)out)[t] = val;
        else    ((u16*)out)[t]   = f2b(val);
    }
}

// ---------- host ----------
extern "C" void kernel_launch(void* const* d_in, const int* in_sizes, int n_in,
                              void* d_out, int out_size, void* d_ws, size_t ws_size,
                              hipStream_t stream){
    const void* x    = d_in[0];
    const int*  edge = (const int*)d_in[1];
    const int E = in_sizes[1]/2;
    const void* W1   = d_in[2];
    const void* as1w = d_in[3];
    const void* ad1w = d_in[4];
    const void* b1   = d_in[5];
    const void* W2   = d_in[6];
    const void* as2w = d_in[7];
    const void* ad2w = d_in[8];
    const void* b2   = d_in[9];
    const void* advw = d_in[10];
    const void* advb = d_in[11];
    const void* v1w  = d_in[12];
    const void* v1b  = d_in[13];
    const void* v2w  = d_in[14];
    const void* v2b  = d_in[15];
    const void* v3w  = d_in[16];
    const void* v3b  = d_in[17];

    char* wsp = (char*)d_ws;
    size_t o = 0;
    auto alloc = [&](size_t bytes)->char*{
        char* p = wsp + o;
        o = (o + bytes + 255) & ~(size_t)255;
        return p;
    };
    int*   flags  = (int*)  alloc(256);
    int*   counts = (int*)  alloc(NODES*4);
    int*   offs   = (int*)  alloc((NODES+8)*4);
    int*   cursor = (int*)  alloc(NODES*4);
    int*   csr    = (int*)  alloc((size_t)E*4);
    float* g1     = (float*)alloc((size_t)NODES*HC1*4);
    float* as1    = (float*)alloc((size_t)NODES*8*4);
    float* ad1    = (float*)alloc((size_t)NODES*8*4);
    float* z1     = (float*)alloc((size_t)NODES*HC1*4);
    u16*   g2     = (u16*)  alloc((size_t)NODES*HC2*2);
    float* as2    = (float*)alloc((size_t)NODES*8*4);
    float* ad2    = (float*)alloc((size_t)NODES*8*4);
    u16*   hbf    = (u16*)  alloc((size_t)NODES*HC2*2);
    float* s1     = (float*)alloc((size_t)4096*512*4);   // 8 MB
    float* s2     = (float*)alloc((size_t)1024*128*4);   // 512 KB
    float* v1a    = (float*)alloc(512*4);
    float* adva   = (float*)alloc(128*4);

    k_prep  <<<33, 256, 0, stream>>>((const u16*)x, edge, flags, counts);
    k_cnt_d1<<<2560, 256, 0, stream>>>(edge, E, counts, x, W1, as1w, ad1w, g1, as1, ad1, flags);
    k_scan  <<<1, 1024, 0, stream>>>(counts, offs, cursor);
    k_fill  <<<(E+255)/256, 256, 0, stream>>>(edge, E, cursor, csr, flags);
    k_agg1  <<<NODES, 64, 0, stream>>>(offs, csr, g1, as1, ad1, b1, z1, flags);
    k_d2a2  <<<NODES/8, 256, 0, stream>>>(z1, W2, as2w, ad2w, g2, as2, ad2, flags);
    k_agg2  <<<NODES, 256, 0, stream>>>(offs, csr, g2, as2, ad2, b2, hbf, flags);
    k_heads <<<1280, 256, 0, stream>>>(v1w, advw, hbf, s1, s2, flags);
    k_reduce<<<10, 1024, 0, stream>>>(s1, s2, v1a, adva);
    k_final <<<1, 512, 0, stream>>>(v1a, adva, v1b, advb, v2w, v2b, v3w, v3b, d_out, flags);
}